// Round 8
// baseline (476.140 us; speedup 1.0000x reference)
//
#include <hip/hip_runtime.h>
#include <math.h>

#define C1C 1e-4f       // 0.01^2
#define C2C 9e-4f       // 0.03^2
// Inputs: (32, 3, 512, 512) fp32; 8x8 patches of 64x64. plane = q*3 + c.
// FOUR-CONV SSIM (basis s=x+y, d=x-y): a=conv(s), b=conv(d), u=conv(s^2),
// v=conv(d^2); 2mu1mu2=(a^2-b^2)/2, mu1^2+mu2^2=(a^2+b^2)/2,
// 2sig12+C2=(u-v)/2-2mu1mu2+C2, sig1+sig2+C2=(u+v)/2-(mu^2sum)+C2.
// MEASURED MODEL (r0-r7): VALU work = 72us; stall ~108us; waves/SIMD =
// floor(256/VGPR) and the allocator pins VGPR at 68-84 regardless of source
// live-set shaping (r3/r6/r7); forced caps (launch_bounds min>=4) spill
// catastrophically. => wave count immovable at 3/SIMD. THIS ROUND: keep 12
// waves/CU but split into SIX 2-wave blocks (vs three 4-wave): double the
// independent sync domains, halve the waves coupled per barrier. Plane is
// processed in FOUR 16-col strips so LDS = 4*74*20*4 = 23680 B -> 6
// blocks/CU. V-pass reads column PAIRS via float2 (ds_read_b64): halves
// LDS instructions; stride 20 makes it 2-way bank aliasing = free
// (even stripes -> banks 0-15, odd -> 16-31).

// Gaussian weights g[k] = exp(-(k-5)^2/4.5)/sum, precomputed in fp64.
#define GW0 0.00102838f
#define GW1 0.00759876f
#define GW2 0.03600077f
#define GW3 0.10936069f
#define GW4 0.21300554f
#define GW5 0.26601173f
__device__ __forceinline__ float conv11(const float* w) {
    // w points at first tap of an 11-wide window
    float a = GW0 * (w[0] + w[10]);
    a = fmaf(GW1, w[1] + w[9], a);
    a = fmaf(GW2, w[2] + w[8], a);
    a = fmaf(GW3, w[3] + w[7], a);
    a = fmaf(GW4, w[4] + w[6], a);
    a = fmaf(GW5, w[5], a);
    return a;
}

#define SROWS 74   // 5 halo + 64 data + 5 halo
#define SSTR  20   // 16 cols + 4 pad; rows 80B (16B-aligned for b128 writes)

// ---------------------------------------------------------------------------
// Fused: per (patch q, channel c) plane: 4 separable 11x11 gaussian convs
// over four 16-col strips, SSIM-map sum, MSE partials.
// grid (2048, 3), block 128 (2 waves). LDS = 23680 B -> 6 blocks/CU.
// ---------------------------------------------------------------------------
__global__ __launch_bounds__(128, 3) void ssim_fused_kernel(
    const float* __restrict__ A,  const float* __restrict__ Nimg,
    const float* __restrict__ GT, const float* __restrict__ G,
    const float* __restrict__ BG,
    float* __restrict__ ssim_sum, float* __restrict__ sa_sum,
    float* __restrict__ sbg_sum)
{
    __shared__ float S0[SROWS][SSTR];   // conv(s^2)
    __shared__ float S1[SROWS][SSTR];   // conv(d^2)
    __shared__ float S2[SROWS][SSTR];   // conv(s)
    __shared__ float S3[SROWS][SSTR];   // conv(d)

    const int q  = blockIdx.x;          // patch 0..2047
    const int c  = blockIdx.y;          // channel 0..2
    const int b  = q >> 6;
    const int pp = q & 63;
    const int ph = pp >> 3;
    const int pw = pp & 7;
    // 32-bit element offsets: whole tensor is 25.2M floats < 2^32.
    const unsigned base = ((unsigned)(b * 3 + c) << 18)
                        + ((unsigned)(ph * 64) << 9)
                        + (unsigned)(pw * 64);
    const int t = threadIdx.x;

    // Zero the 5-row top/bottom halos of all four buffers (once; H-pass
    // writes only rows 5..68 and V-pass never writes, so halos persist).
    for (int i = t; i < 10 * SSTR; i += 128) {
        const int r  = i / SSTR;
        const int cc = i - r * SSTR;
        const int rr = (r < 5) ? r : 64 + r;        // rows 0..4, 69..73
        S0[rr][cc] = 0.f; S1[rr][cc] = 0.f;
        S2[rr][cc] = 0.f; S3[rr][cc] = 0.f;
    }

    // Horizontal mapping: thread -> (row hr 0..63, 8-col group hg 0 or 8)
    const int hr = t >> 1;
    const int hg = (t & 1) << 3;              // strip-local col base
    const unsigned rowBase = base + ((unsigned)hr << 9);
    // Vertical mapping: thread -> (col pair vp 0,2..14, 4-row stripe vr0)
    const int vp  = (t & 7) << 1;
    const int vr0 = (t >> 3) << 2;            // 0,4,...,60 (padded start)

    float accS = 0.f;

    for (int h = 0; h < 4; ++h) {
        const int g0 = (h << 4) + hg;         // global col of first output
        // ---------------- Horizontal pass (one strip) ----------------------
        // Window taps for global cols g0-5 .. g0+12 (18 floats); aligned
        // float4 loads cover g0-8 .. g0+15, extras discarded at compile time.
        float s[18], d[18];
        #pragma unroll
        for (int m = 0; m < 6; ++m) {
            const int cb = g0 - 8 + 4 * m;    // global col of this float4
            float4 xv = make_float4(0.f, 0.f, 0.f, 0.f);
            float4 yv = make_float4(0.f, 0.f, 0.f, 0.f);
            if (cb >= 0 && cb < 64) {         // zero pad outside patch
                xv = *(const float4*)(Nimg + rowBase + cb);
                yv = *(const float4*)(GT   + rowBase + cb);
            }
            #pragma unroll
            for (int u = 0; u < 4; ++u) {
                const int j = 4 * m + u - 3;  // window index (col g0-5+j)
                if (j >= 0 && j < 18) {
                    s[j] = (&xv.x)[u] + (&yv.x)[u];
                    d[j] = (&xv.x)[u] - (&yv.x)[u];
                }
            }
        }

        // conv(s) -> S2, square s in place, conv(s^2) -> S0;
        // conv(d) -> S3, square d in place, conv(d^2) -> S1.
        #pragma unroll
        for (int mm = 0; mm < 2; ++mm) {
            float4 o;
            #pragma unroll
            for (int u = 0; u < 4; ++u) (&o.x)[u] = conv11(&s[4*mm + u]);
            *(float4*)&S2[5 + hr][hg + 4*mm] = o;
        }
        #pragma unroll
        for (int i = 0; i < 18; ++i) s[i] = s[i] * s[i];
        #pragma unroll
        for (int mm = 0; mm < 2; ++mm) {
            float4 o;
            #pragma unroll
            for (int u = 0; u < 4; ++u) (&o.x)[u] = conv11(&s[4*mm + u]);
            *(float4*)&S0[5 + hr][hg + 4*mm] = o;
        }
        #pragma unroll
        for (int mm = 0; mm < 2; ++mm) {
            float4 o;
            #pragma unroll
            for (int u = 0; u < 4; ++u) (&o.x)[u] = conv11(&d[4*mm + u]);
            *(float4*)&S3[5 + hr][hg + 4*mm] = o;
        }
        #pragma unroll
        for (int i = 0; i < 18; ++i) d[i] = d[i] * d[i];
        #pragma unroll
        for (int mm = 0; mm < 2; ++mm) {
            float4 o;
            #pragma unroll
            for (int u = 0; u < 4; ++u) (&o.x)[u] = conv11(&d[4*mm + u]);
            *(float4*)&S1[5 + hr][hg + 4*mm] = o;
        }
        __syncthreads();

        // ---------------- Vertical pass: 4 convs + SSIM --------------------
        // Each thread: 2 adjacent cols (float2 reads) x 4 output rows.
        {
            float w0[14], w1[14];
            float t2[8], ss[8], uv[8];   // [0..3]=col vp, [4..7]=col vp+1
            #pragma unroll
            for (int dd = 0; dd < 14; ++dd) {
                const float2 rv = *(const float2*)&S2[vr0 + dd][vp];
                w0[dd] = rv.x; w1[dd] = rv.y;
            }
            #pragma unroll
            for (int o = 0; o < 4; ++o) {        // a = mu1+mu2 (temp in t2)
                t2[o]     = conv11(&w0[o]);
                t2[4 + o] = conv11(&w1[o]);
            }
            #pragma unroll
            for (int dd = 0; dd < 14; ++dd) {
                const float2 rv = *(const float2*)&S3[vr0 + dd][vp];
                w0[dd] = rv.x; w1[dd] = rv.y;
            }
            #pragma unroll
            for (int o = 0; o < 4; ++o) {        // b = mu1-mu2, fold
                float bb = conv11(&w0[o]);
                float A2 = t2[o] * t2[o], B2 = bb * bb;
                t2[o] = 0.5f * (A2 - B2);        // 2*mu1*mu2
                ss[o] = 0.5f * (A2 + B2);        // mu1^2+mu2^2
                bb = conv11(&w1[o]);
                A2 = t2[4+o] * t2[4+o]; B2 = bb * bb;
                t2[4+o] = 0.5f * (A2 - B2);
                ss[4+o] = 0.5f * (A2 + B2);
            }
            #pragma unroll
            for (int dd = 0; dd < 14; ++dd) {
                const float2 rv = *(const float2*)&S0[vr0 + dd][vp];
                w0[dd] = rv.x; w1[dd] = rv.y;
            }
            #pragma unroll
            for (int o = 0; o < 4; ++o) {        // u = conv(s^2)
                uv[o]     = conv11(&w0[o]);
                uv[4 + o] = conv11(&w1[o]);
            }
            #pragma unroll
            for (int dd = 0; dd < 14; ++dd) {
                const float2 rv = *(const float2*)&S1[vr0 + dd][vp];
                w0[dd] = rv.x; w1[dd] = rv.y;
            }
            #pragma unroll
            for (int o = 0; o < 4; ++o) {        // v = conv(d^2), combine
                const float vvv  = conv11(&w0[o]);
                const float numL = t2[o] + C1C;
                const float denL = ss[o] + C1C;
                const float numR = fmaf(0.5f, uv[o] - vvv, C2C - t2[o]);
                const float denR = fmaf(0.5f, uv[o] + vvv, C2C - ss[o]);
                accS += (numL * numR) * __builtin_amdgcn_rcpf(denL * denR);
            }
            #pragma unroll
            for (int o = 0; o < 4; ++o) {
                const float vvv  = conv11(&w1[o]);
                const float numL = t2[4+o] + C1C;
                const float denL = ss[4+o] + C1C;
                const float numR = fmaf(0.5f, uv[4+o] - vvv, C2C - t2[4+o]);
                const float denR = fmaf(0.5f, uv[4+o] + vvv, C2C - ss[4+o]);
                accS += (numL * numR) * __builtin_amdgcn_rcpf(denL * denR);
            }
        }
        __syncthreads();      // buffers free for next strip (or reduction)
    }

    // ---------------- Fused MSE partials over this plane -------------------
    float sa = 0.f, sbg = 0.f;
    #pragma unroll
    for (int it = 0; it < 8; ++it) {
        const int idx  = t + 128 * it;        // 0..1023 float4 slots
        const int row  = idx >> 4;
        const int col4 = (idx & 15) << 2;
        const unsigned off = base + ((unsigned)row << 9) + col4;
        const float4 av  = *(const float4*)(A  + off);
        const float4 gv  = *(const float4*)(G  + off);
        const float4 bgv = *(const float4*)(BG + off);
        float d0 = bgv.x - gv.x, d1 = bgv.y - gv.y, d2 = bgv.z - gv.z, d3 = bgv.w - gv.w;
        sbg += d0*d0 + d1*d1 + d2*d2 + d3*d3;
        float e0 = av.x - gv.x, e1 = av.y - gv.y, e2 = av.z - gv.z, e3 = av.w - gv.w;
        sa  += e0*e0 + e1*e1 + e2*e2 + e3*e3;
    }

    // ---------------- Block reduction of (accS, sa, sbg) -------------------
    #pragma unroll
    for (int off = 32; off; off >>= 1) {
        accS += __shfl_down(accS, off, 64);
        sa   += __shfl_down(sa,   off, 64);
        sbg  += __shfl_down(sbg,  off, 64);
    }
    const int wv = t >> 6;                    // wave 0 or 1
    if ((t & 63) == 0) {
        S0[0][wv] = accS; S0[1][wv] = sa; S0[2][wv] = sbg;
    }
    __syncthreads();
    if (t == 0) {
        const int plane = q * 3 + c;
        ssim_sum[plane] = S0[0][0] + S0[0][1];
        sa_sum[plane]   = S0[1][0] + S0[1][1];
        sbg_sum[plane]  = S0[2][0] + S0[2][1];
    }
}

// ---------------------------------------------------------------------------
// Final combine: 1 block, 256 threads, no atomics, deterministic.
// ---------------------------------------------------------------------------
__global__ __launch_bounds__(256) void combine_kernel(
    const float* __restrict__ ssim_sum, const float* __restrict__ sa_sum,
    const float* __restrict__ sbg_sum, float* __restrict__ out)
{
    __shared__ float red[4];
    const int t = threadIdx.x;
    const float invN = 1.f / 12288.f;     // 3*64*64
    float acc = 0.f;
    #pragma unroll
    for (int r = 0; r < 8; ++r) {
        const int qq = t + 256 * r;       // patch 0..2047
        const float ss = ssim_sum[3*qq] + ssim_sum[3*qq+1] + ssim_sum[3*qq+2];
        const float sa = sa_sum[3*qq]   + sa_sum[3*qq+1]   + sa_sum[3*qq+2];
        const float sb = sbg_sum[3*qq]  + sbg_sum[3*qq+1]  + sbg_sum[3*qq+2];
        const float ssim = ss * invN;
        const float diff = fminf(1.f - ssim, 1.f);     // LD = 1.0
        acc += diff * (sb * invN) + (1.f - diff) * (sa * invN);
    }
    #pragma unroll
    for (int off = 32; off; off >>= 1) acc += __shfl_down(acc, off, 64);
    if ((t & 63) == 0) red[t >> 6] = acc;
    __syncthreads();
    if (t == 0) out[0] = red[0] + red[1] + red[2] + red[3];
}

extern "C" void kernel_launch(void* const* d_in, const int* in_sizes, int n_in,
                              void* d_out, int out_size, void* d_ws, size_t ws_size,
                              hipStream_t stream) {
    const float* A  = (const float*)d_in[0];
    const float* Nn = (const float*)d_in[1];
    const float* GT = (const float*)d_in[2];
    const float* G  = (const float*)d_in[3];
    const float* BG = (const float*)d_in[4];
    float* out      = (float*)d_out;

    float* ssim_sum = (float*)d_ws;            // 6144 floats
    float* sa_sum   = ssim_sum + 6144;         // 6144 floats
    float* sbg_sum  = ssim_sum + 12288;        // 6144 floats

    ssim_fused_kernel<<<dim3(2048, 3), 128, 0, stream>>>(
        A, Nn, GT, G, BG, ssim_sum, sa_sum, sbg_sum);
    combine_kernel<<<1, 256, 0, stream>>>(ssim_sum, sa_sum, sbg_sum, out);
}